// Round 5
// baseline (3679.710 us; speedup 1.0000x reference)
//
#include <hip/hip_runtime.h>
#include <cstdint>

typedef __bf16 bf16x8 __attribute__((ext_vector_type(8)));
typedef float  f32x4  __attribute__((ext_vector_type(4)));

union U4B { uint4 u; bf16x8 b; };
__device__ __forceinline__ bf16x8 as_bf(uint4 u) { U4B x; x.u = u; return x.b; }

// float -> bf16 bits, round-to-nearest-even (finite inputs)
__device__ __forceinline__ unsigned short f2b(float x) {
  unsigned int u = __float_as_uint(x);
  unsigned int r = (u + 0x7fffu + ((u >> 16) & 1u)) >> 16;
  return (unsigned short)r;
}
__device__ __forceinline__ float b2f(unsigned int bits_lo16) {
  return __uint_as_float(bits_lo16 << 16);
}

__device__ __forceinline__ float sigm(float x) {
  float e = __builtin_amdgcn_exp2f(x * -1.4426950408889634f);
  return __builtin_amdgcn_rcpf(1.0f + e);
}
__device__ __forceinline__ float tanh_fast(float x) {
  float e = __builtin_amdgcn_exp2f(x * 2.8853900817779268f);
  return 1.0f - 2.0f * __builtin_amdgcn_rcpf(e + 1.0f);
}

// ---------------- prep: build permuted bf16 weight layouts in ws ----------------
// recT [1024 col'][256 k]   : col' = 4u+g  <-> orig col = u + 256g
// kb2  [128 ch][1024 col']  : (kernel + bias) same permutation
// dwT  [128 class][256 k]   : dense_w transposed
__global__ void prep_kernel(const float* __restrict__ rec,
                            const float* __restrict__ kern,
                            const float* __restrict__ bias,
                            const float* __restrict__ dw,
                            unsigned short* __restrict__ recT,
                            unsigned short* __restrict__ kb2,
                            unsigned short* __restrict__ dwT) {
  int id = blockIdx.x * 256 + threadIdx.x;
  if (id < 262144) {                       // 1024*256
    int colp = id >> 8, k = id & 255;
    int u = colp >> 2, g = colp & 3;
    recT[colp * 256 + k] = f2b(rec[k * 1024 + u + 256 * g]);
  } else if (id < 262144 + 131072) {       // 128*1024
    int i = id - 262144;
    int ch = i >> 10, colp = i & 1023;
    int u = colp >> 2, g = colp & 3;
    int oc = u + 256 * g;
    kb2[ch * 1024 + colp] = f2b(kern[ch * 1024 + oc] + bias[oc]);
  } else {                                 // 128*256
    int i = id - 262144 - 131072;
    int cls = i >> 8, k = i & 255;
    dwT[cls * 256 + k] = f2b(dw[k * 128 + cls]);
  }
}

// ---------------- main persistent LSTM kernel ----------------
// 64 blocks x 512 threads (8 waves, EXACTLY 2 waves/EU so allocator may use
// 256 VGPRs). Block owns 16 batch rows for all 512 steps.
// Wave wid owns gate-cols [wid*128, wid*128+128) = 8 m-tiles:
//   m 0..2 : A fragments resident in VGPRs (96 regs, pinned)
//   m 3..4 : A fragments in LDS (per-wave-private, 128 KB/block)
//   m 5..7 : A streamed from L2 each step (rotating window-3 prefetch)
// z^T tile: D col = batch row (lane&15); D rows = gates i,f,g,o of
// unit u = wid*32 + m*4 + (lane>>4).
__global__ __launch_bounds__(512)
__attribute__((amdgpu_waves_per_eu(2, 2)))
void lstm_kernel(
    const unsigned short* __restrict__ recT,
    const unsigned short* __restrict__ kb2,
    const unsigned short* __restrict__ dwT,
    const int* __restrict__ x,
    const float* __restrict__ dense_b,
    float* __restrict__ out) {
  __shared__ uint4 A_lds[2][8][512];            // 128 KB, [slot][k][wid*64+lane]
  __shared__ unsigned short h_buf[2][16][264];  // 16.9 KB bf16 h, padded rows

  const int tid   = threadIdx.x;
  const int lane  = tid & 63;
  const int wid   = tid >> 6;      // 0..7
  const int row16 = lane & 15;     // batch row within tile / A-frag row
  const int kg    = lane >> 4;     // 0..3 k-group
  const int rbase = blockIdx.x << 4;

  // per-lane A base: col' = wid*128 + row16 (+ m*16), k = kg*8 (+ k*32)
  const unsigned short* recBase = recT + ((wid * 128 + row16) * 256 + kg * 8);

  // ---- A regs: m = 0..2, loaded once, pinned (per-component scalar ties) ----
  uint4 af[3][8];
#pragma unroll
  for (int m = 0; m < 3; ++m)
#pragma unroll
    for (int k = 0; k < 8; ++k) {
      af[m][k] = *(const uint4*)(recBase + m * 4096 + k * 32);
      asm volatile("" : "+v"(af[m][k].x), "+v"(af[m][k].y),
                        "+v"(af[m][k].z), "+v"(af[m][k].w));
    }

  // ---- A LDS: m = 3..4, per-wave-private slots, staged once ----
#pragma unroll
  for (int s = 0; s < 2; ++s)
#pragma unroll
    for (int k = 0; k < 8; ++k)
      A_lds[s][k][wid * 64 + lane] = *(const uint4*)(recBase + (3 + s) * 4096 + k * 32);

  // ---- stream bases: m = 5..7, rotating window-3 (slot = frag_k % 3) ----
  const unsigned short* sb5 = recBase + 5 * 4096;
  const unsigned short* sb6 = recBase + 6 * 4096;
  const unsigned short* sb7 = recBase + 7 * 4096;
  uint4 st5[3], st6[3], st7[3];
#pragma unroll
  for (int k = 0; k < 3; ++k) {
    st5[k] = *(const uint4*)(sb5 + k * 32);
    st6[k] = *(const uint4*)(sb6 + k * 32);
    st7[k] = *(const uint4*)(sb7 + k * 32);
  }

  // zero h(0)
  for (int e = tid; e < 16 * 264; e += 512) (&h_buf[0][0][0])[e] = 0;

  float c_state[8];
#pragma unroll
  for (int m = 0; m < 8; ++m) c_state[m] = 0.0f;

  const int* xrow = x + (rbase + row16) * 512;
  int idx_cur = xrow[0];

  __syncthreads();

  int cur = 0;
  const unsigned aoff_base = (wid * 64 + lane) * 16;  // byte offset in each [s][k] plane

#pragma unroll 1
  for (int t = 0; t < 512; ++t) {
    // laundered zero offsets: defeat LICM/remat of stream & LDS-tile loads
    unsigned z6 = 0, zL = 0;
    asm volatile("" : "+v"(z6), "+v"(zL));
    const unsigned short* sb5v = sb5 + z6;
    const unsigned short* sb6v = sb6 + z6;
    const unsigned short* sb7v = sb7 + z6;
    const unsigned aoff = aoff_base + zL;

    int idx_next = xrow[(t + 1 < 512) ? t + 1 : 511];

    const unsigned short* hrow = &h_buf[cur][row16][0];
    const unsigned short* kb = kb2 + (idx_cur * 1024 + wid * 128 + kg * 4);
    uint2 kq[8];

    f32x4 acc[8];
#pragma unroll
    for (int m = 0; m < 8; ++m) acc[m] = f32x4{0.f, 0.f, 0.f, 0.f};

#pragma unroll
    for (int k = 0; k < 8; ++k) {
      uint4 hf = *(const uint4*)(hrow + k * 32 + kg * 8);
      acc[0] = __builtin_amdgcn_mfma_f32_16x16x32_bf16(as_bf(af[0][k]), as_bf(hf), acc[0], 0, 0, 0);
      acc[1] = __builtin_amdgcn_mfma_f32_16x16x32_bf16(as_bf(af[1][k]), as_bf(hf), acc[1], 0, 0, 0);
      acc[2] = __builtin_amdgcn_mfma_f32_16x16x32_bf16(as_bf(af[2][k]), as_bf(hf), acc[2], 0, 0, 0);
      uint4 a3 = *(const uint4*)((const char*)A_lds + (0 * 8 + k) * 8192 + aoff);
      acc[3] = __builtin_amdgcn_mfma_f32_16x16x32_bf16(as_bf(a3), as_bf(hf), acc[3], 0, 0, 0);
      uint4 a4 = *(const uint4*)((const char*)A_lds + (1 * 8 + k) * 8192 + aoff);
      acc[4] = __builtin_amdgcn_mfma_f32_16x16x32_bf16(as_bf(a4), as_bf(hf), acc[4], 0, 0, 0);
      acc[5] = __builtin_amdgcn_mfma_f32_16x16x32_bf16(as_bf(st5[k % 3]), as_bf(hf), acc[5], 0, 0, 0);
      acc[6] = __builtin_amdgcn_mfma_f32_16x16x32_bf16(as_bf(st6[k % 3]), as_bf(hf), acc[6], 0, 0, 0);
      acc[7] = __builtin_amdgcn_mfma_f32_16x16x32_bf16(as_bf(st7[k % 3]), as_bf(hf), acc[7], 0, 0, 0);
      // rotating prefetch: frag (k+3)&7 into slot ((k+3)&7)%3 == (k%3)
      const int kp = (k + 3) & 7;
      st5[k % 3] = *(const uint4*)(sb5v + kp * 32);
      st6[k % 3] = *(const uint4*)(sb6v + kp * 32);
      st7[k % 3] = *(const uint4*)(sb7v + kp * 32);
      if (k == 1) {  // issue kq gather early; consumed only in gate phase
#pragma unroll
        for (int m = 0; m < 8; ++m) kq[m] = *(const uint2*)(kb + m * 16);
      }
    }

    // elementwise LSTM update, fully in-register
    unsigned short* hn = &h_buf[cur ^ 1][row16][wid * 32 + kg];
#pragma unroll
    for (int m = 0; m < 8; ++m) {
      float zi = acc[m][0] + b2f(kq[m].x & 0xffffu);
      float zf = acc[m][1] + b2f(kq[m].x >> 16);
      float zg = acc[m][2] + b2f(kq[m].y & 0xffffu);
      float zo = acc[m][3] + b2f(kq[m].y >> 16);
      float gi = sigm(zi);
      float gf = sigm(zf);
      float gg = tanh_fast(zg);
      float go = sigm(zo);
      float c  = gf * c_state[m] + gi * gg;
      c_state[m] = c;
      float h  = go * tanh_fast(c);
      hn[m * 4] = f2b(h);
    }
    __syncthreads();
    cur ^= 1;
    idx_cur = idx_next;
  }

  // ---- final dense (MFMA) + softmax; final h is in h_buf[0] (512 steps, even) ----
  float (*l_lds)[132] = (float (*)[132])A_lds;  // overlay logits onto A_lds region
  {
    const unsigned short* dwBase = dwT + ((wid * 16 + row16) * 256 + kg * 8);
    uint4 hf[8];
#pragma unroll
    for (int k = 0; k < 8; ++k)
      hf[k] = *(const uint4*)&h_buf[0][row16][k * 32 + kg * 8];
    f32x4 la = {0.f, 0.f, 0.f, 0.f};
#pragma unroll
    for (int k = 0; k < 8; ++k) {
      uint4 afd = *(const uint4*)(dwBase + k * 32);
      la = __builtin_amdgcn_mfma_f32_16x16x32_bf16(as_bf(afd), as_bf(hf[k]), la, 0, 0, 0);
    }
#pragma unroll
    for (int r = 0; r < 4; ++r) {
      int cls = wid * 16 + kg * 4 + r;
      l_lds[row16][cls] = la[r] + dense_b[cls];
    }
  }
  __syncthreads();

  {
    int r = tid >> 5, cg = tid & 31;   // 16 rows x 32 col-groups of 4
    float4 v = *(const float4*)&l_lds[r][cg * 4];
    float mx = fmaxf(fmaxf(v.x, v.y), fmaxf(v.z, v.w));
#pragma unroll
    for (int s = 1; s < 32; s <<= 1) mx = fmaxf(mx, __shfl_xor(mx, s));
    const float L2E = 1.4426950408889634f;
    float e0 = __builtin_amdgcn_exp2f((v.x - mx) * L2E);
    float e1 = __builtin_amdgcn_exp2f((v.y - mx) * L2E);
    float e2 = __builtin_amdgcn_exp2f((v.z - mx) * L2E);
    float e3 = __builtin_amdgcn_exp2f((v.w - mx) * L2E);
    float sm = e0 + e1 + e2 + e3;
#pragma unroll
    for (int s = 1; s < 32; s <<= 1) sm += __shfl_xor(sm, s);
    float inv = __builtin_amdgcn_rcpf(sm);
    float4 o = {e0 * inv, e1 * inv, e2 * inv, e3 * inv};
    *(float4*)&out[(rbase + r) * 128 + cg * 4] = o;
  }
}

extern "C" void kernel_launch(void* const* d_in, const int* in_sizes, int n_in,
                              void* d_out, int out_size, void* d_ws, size_t ws_size,
                              hipStream_t stream) {
  const int*   x      = (const int*)d_in[0];    // [1024][512] int32
  const float* kern   = (const float*)d_in[1];  // [128][1024]
  const float* rec    = (const float*)d_in[2];  // [256][1024]
  const float* bias   = (const float*)d_in[3];  // [1024]
  const float* dw     = (const float*)d_in[4];  // [256][128]
  const float* db     = (const float*)d_in[5];  // [128]
  float* outp = (float*)d_out;                  // [1024][128]

  unsigned char* ws = (unsigned char*)d_ws;
  unsigned short* recT = (unsigned short*)(ws);            // 512 KB
  unsigned short* kb2  = (unsigned short*)(ws + 524288);   // 256 KB
  unsigned short* dwT  = (unsigned short*)(ws + 786432);   //  64 KB

  prep_kernel<<<1664, 256, 0, stream>>>(rec, kern, bias, dw, recT, kb2, dwT);
  lstm_kernel<<<64, 512, 0, stream>>>(recT, kb2, dwT, x, db, outp);
}

// Round 6
// 3643.209 us; speedup vs baseline: 1.0100x; 1.0100x over previous
//
#include <hip/hip_runtime.h>
#include <cstdint>

typedef __bf16 bf16x8 __attribute__((ext_vector_type(8)));
typedef float  f32x4  __attribute__((ext_vector_type(4)));

union U4B { uint4 u; bf16x8 b; };
__device__ __forceinline__ bf16x8 as_bf(uint4 u) { U4B x; x.u = u; return x.b; }

// float -> bf16 bits, round-to-nearest-even (finite inputs)
__device__ __forceinline__ unsigned short f2b(float x) {
  unsigned int u = __float_as_uint(x);
  unsigned int r = (u + 0x7fffu + ((u >> 16) & 1u)) >> 16;
  return (unsigned short)r;
}
__device__ __forceinline__ float b2f(unsigned int bits_lo16) {
  return __uint_as_float(bits_lo16 << 16);
}

__device__ __forceinline__ float sigm(float x) {
  float e = __builtin_amdgcn_exp2f(x * -1.4426950408889634f);
  return __builtin_amdgcn_rcpf(1.0f + e);
}
__device__ __forceinline__ float tanh_fast(float x) {
  float e = __builtin_amdgcn_exp2f(x * 2.8853900817779268f);
  return 1.0f - 2.0f * __builtin_amdgcn_rcpf(e + 1.0f);
}

// ---------------- prep: build permuted bf16 weight layouts in ws ----------------
// recT [1024 col'][256 k]   : col' = 4u+g  <-> orig col = u + 256g
// kb2  [128 ch][1024 col']  : (kernel + bias) same permutation
// dwT  [128 class][256 k]   : dense_w transposed
__global__ void prep_kernel(const float* __restrict__ rec,
                            const float* __restrict__ kern,
                            const float* __restrict__ bias,
                            const float* __restrict__ dw,
                            unsigned short* __restrict__ recT,
                            unsigned short* __restrict__ kb2,
                            unsigned short* __restrict__ dwT) {
  int id = blockIdx.x * 256 + threadIdx.x;
  if (id < 262144) {                       // 1024*256
    int colp = id >> 8, k = id & 255;
    int u = colp >> 2, g = colp & 3;
    recT[colp * 256 + k] = f2b(rec[k * 1024 + u + 256 * g]);
  } else if (id < 262144 + 131072) {       // 128*1024
    int i = id - 262144;
    int ch = i >> 10, colp = i & 1023;
    int u = colp >> 2, g = colp & 3;
    int oc = u + 256 * g;
    kb2[ch * 1024 + colp] = f2b(kern[ch * 1024 + oc] + bias[oc]);
  } else {                                 // 128*256
    int i = id - 262144 - 131072;
    int cls = i >> 8, k = i & 255;
    dwT[cls * 256 + k] = f2b(dw[k * 128 + cls]);
  }
}

// ---------------- main persistent LSTM kernel ----------------
// 64 blocks x 512 threads (8 waves = 2/SIMD, so 256 unified regs/wave).
// Block owns 16 batch rows for all 512 steps.
// Wave wid owns gate-cols [wid*128, wid*128+128) = 8 m-tiles:
//   m 0..2 : A fragments pinned in AGPRs (96 accum regs; MFMA reads them in place)
//   m 3..4 : A fragments in LDS (per-wave-private, 128 KB/block)
//   m 5..7 : A streamed from L2 each step (window-4 rotating prefetch; 4|8 so
//            the slot<->frag mapping is phase-aligned across steps)
// z^T tile: D col = batch row (lane&15); D rows = gates i,f,g,o of
// unit u = wid*32 + m*4 + (lane>>4).
__global__ __launch_bounds__(512)
__attribute__((amdgpu_waves_per_eu(2, 2)))
void lstm_kernel(
    const unsigned short* __restrict__ recT,
    const unsigned short* __restrict__ kb2,
    const unsigned short* __restrict__ dwT,
    const int* __restrict__ x,
    const float* __restrict__ dense_b,
    float* __restrict__ out) {
  __shared__ uint4 A_lds[2][8][512];            // 128 KB, [slot][k][wid*64+lane]
  __shared__ unsigned short h_buf[2][16][264];  // 16.9 KB bf16 h, padded rows

  const int tid   = threadIdx.x;
  const int lane  = tid & 63;
  const int wid   = tid >> 6;      // 0..7
  const int row16 = lane & 15;     // batch row within tile / A-frag row
  const int kg    = lane >> 4;     // 0..3 k-group
  const int rbase = blockIdx.x << 4;

  // per-lane A base: col' = wid*128 + row16 (+ m*16), k = kg*8 (+ k*32)
  const unsigned short* recBase = recT + ((wid * 128 + row16) * 256 + kg * 8);

  // ---- A regs: m = 0..2, loaded once, pinned into AGPRs (per-component) ----
  uint4 af[3][8];
#pragma unroll
  for (int m = 0; m < 3; ++m)
#pragma unroll
    for (int k = 0; k < 8; ++k) {
      af[m][k] = *(const uint4*)(recBase + m * 4096 + k * 32);
      asm volatile("" : "+a"(af[m][k].x), "+a"(af[m][k].y),
                        "+a"(af[m][k].z), "+a"(af[m][k].w));
    }

  // ---- A LDS: m = 3..4, per-wave-private slots, staged once ----
#pragma unroll
  for (int s = 0; s < 2; ++s)
#pragma unroll
    for (int k = 0; k < 8; ++k)
      A_lds[s][k][wid * 64 + lane] = *(const uint4*)(recBase + (3 + s) * 4096 + k * 32);

  // ---- stream bases: m = 5..7, window-4 (slot = frag & 3; 4 divides 8) ----
  const unsigned short* sb5 = recBase + 5 * 4096;
  const unsigned short* sb6 = recBase + 6 * 4096;
  const unsigned short* sb7 = recBase + 7 * 4096;
  uint4 st5[4], st6[4], st7[4];
#pragma unroll
  for (int k = 0; k < 4; ++k) {
    st5[k] = *(const uint4*)(sb5 + k * 32);
    st6[k] = *(const uint4*)(sb6 + k * 32);
    st7[k] = *(const uint4*)(sb7 + k * 32);
  }

  // zero h(0)
  for (int e = tid; e < 16 * 264; e += 512) (&h_buf[0][0][0])[e] = 0;

  float c_state[8];
#pragma unroll
  for (int m = 0; m < 8; ++m) c_state[m] = 0.0f;

  const int* xrow = x + (rbase + row16) * 512;
  int idx_cur = xrow[0];

  __syncthreads();

  int cur = 0;
  const unsigned aoff_base = (wid * 64 + lane) * 16;  // byte offset in each [s][k] plane

#pragma unroll 1
  for (int t = 0; t < 512; ++t) {
    // laundered zero offsets: defeat LICM/remat of stream & LDS-tile loads
    unsigned z6 = 0, zL = 0;
    asm volatile("" : "+v"(z6), "+v"(zL));
    const unsigned short* sb5v = sb5 + z6;
    const unsigned short* sb6v = sb6 + z6;
    const unsigned short* sb7v = sb7 + z6;
    const unsigned aoff = aoff_base + zL;

    int idx_next = xrow[(t + 1 < 512) ? t + 1 : 511];

    const unsigned short* hrow = &h_buf[cur][row16][0];
    const unsigned short* kb = kb2 + (idx_cur * 1024 + wid * 128 + kg * 4);
    uint2 kq[8];

    f32x4 acc[8];
#pragma unroll
    for (int m = 0; m < 8; ++m) acc[m] = f32x4{0.f, 0.f, 0.f, 0.f};

#pragma unroll
    for (int k = 0; k < 8; ++k) {
      uint4 hf = *(const uint4*)(hrow + k * 32 + kg * 8);
      acc[0] = __builtin_amdgcn_mfma_f32_16x16x32_bf16(as_bf(af[0][k]), as_bf(hf), acc[0], 0, 0, 0);
      acc[1] = __builtin_amdgcn_mfma_f32_16x16x32_bf16(as_bf(af[1][k]), as_bf(hf), acc[1], 0, 0, 0);
      acc[2] = __builtin_amdgcn_mfma_f32_16x16x32_bf16(as_bf(af[2][k]), as_bf(hf), acc[2], 0, 0, 0);
      uint4 a3 = *(const uint4*)((const char*)A_lds + (0 * 8 + k) * 8192 + aoff);
      acc[3] = __builtin_amdgcn_mfma_f32_16x16x32_bf16(as_bf(a3), as_bf(hf), acc[3], 0, 0, 0);
      uint4 a4 = *(const uint4*)((const char*)A_lds + (1 * 8 + k) * 8192 + aoff);
      acc[4] = __builtin_amdgcn_mfma_f32_16x16x32_bf16(as_bf(a4), as_bf(hf), acc[4], 0, 0, 0);
      acc[5] = __builtin_amdgcn_mfma_f32_16x16x32_bf16(as_bf(st5[k & 3]), as_bf(hf), acc[5], 0, 0, 0);
      acc[6] = __builtin_amdgcn_mfma_f32_16x16x32_bf16(as_bf(st6[k & 3]), as_bf(hf), acc[6], 0, 0, 0);
      acc[7] = __builtin_amdgcn_mfma_f32_16x16x32_bf16(as_bf(st7[k & 3]), as_bf(hf), acc[7], 0, 0, 0);
      // window-4 prefetch: frag (k+4)&7 into slot ((k+4)&3) == (k&3).
      // A is time-invariant, and 4|8 keeps slot->frag phase-aligned each step.
      const int kp = (k + 4) & 7;
      st5[k & 3] = *(const uint4*)(sb5v + kp * 32);
      st6[k & 3] = *(const uint4*)(sb6v + kp * 32);
      st7[k & 3] = *(const uint4*)(sb7v + kp * 32);
      if (k == 1) {  // issue kq gather early; consumed only in gate phase
#pragma unroll
        for (int m = 0; m < 8; ++m) kq[m] = *(const uint2*)(kb + m * 16);
      }
    }

    // elementwise LSTM update, fully in-register
    unsigned short* hn = &h_buf[cur ^ 1][row16][wid * 32 + kg];
#pragma unroll
    for (int m = 0; m < 8; ++m) {
      float zi = acc[m][0] + b2f(kq[m].x & 0xffffu);
      float zf = acc[m][1] + b2f(kq[m].x >> 16);
      float zg = acc[m][2] + b2f(kq[m].y & 0xffffu);
      float zo = acc[m][3] + b2f(kq[m].y >> 16);
      float gi = sigm(zi);
      float gf = sigm(zf);
      float gg = tanh_fast(zg);
      float go = sigm(zo);
      float c  = gf * c_state[m] + gi * gg;
      c_state[m] = c;
      float h  = go * tanh_fast(c);
      hn[m * 4] = f2b(h);
    }
    __syncthreads();
    cur ^= 1;
    idx_cur = idx_next;
  }

  // ---- final dense (MFMA) + softmax; final h is in h_buf[0] (512 steps, even) ----
  float (*l_lds)[132] = (float (*)[132])A_lds;  // overlay logits onto A_lds region
  {
    const unsigned short* dwBase = dwT + ((wid * 16 + row16) * 256 + kg * 8);
    uint4 hf[8];
#pragma unroll
    for (int k = 0; k < 8; ++k)
      hf[k] = *(const uint4*)&h_buf[0][row16][k * 32 + kg * 8];
    f32x4 la = {0.f, 0.f, 0.f, 0.f};
#pragma unroll
    for (int k = 0; k < 8; ++k) {
      uint4 afd = *(const uint4*)(dwBase + k * 32);
      la = __builtin_amdgcn_mfma_f32_16x16x32_bf16(as_bf(afd), as_bf(hf[k]), la, 0, 0, 0);
    }
#pragma unroll
    for (int r = 0; r < 4; ++r) {
      int cls = wid * 16 + kg * 4 + r;
      l_lds[row16][cls] = la[r] + dense_b[cls];
    }
  }
  __syncthreads();

  {
    int r = tid >> 5, cg = tid & 31;   // 16 rows x 32 col-groups of 4
    float4 v = *(const float4*)&l_lds[r][cg * 4];
    float mx = fmaxf(fmaxf(v.x, v.y), fmaxf(v.z, v.w));
#pragma unroll
    for (int s = 1; s < 32; s <<= 1) mx = fmaxf(mx, __shfl_xor(mx, s));
    const float L2E = 1.4426950408889634f;
    float e0 = __builtin_amdgcn_exp2f((v.x - mx) * L2E);
    float e1 = __builtin_amdgcn_exp2f((v.y - mx) * L2E);
    float e2 = __builtin_amdgcn_exp2f((v.z - mx) * L2E);
    float e3 = __builtin_amdgcn_exp2f((v.w - mx) * L2E);
    float sm = e0 + e1 + e2 + e3;
#pragma unroll
    for (int s = 1; s < 32; s <<= 1) sm += __shfl_xor(sm, s);
    float inv = __builtin_amdgcn_rcpf(sm);
    float4 o = {e0 * inv, e1 * inv, e2 * inv, e3 * inv};
    *(float4*)&out[(rbase + r) * 128 + cg * 4] = o;
  }
}

extern "C" void kernel_launch(void* const* d_in, const int* in_sizes, int n_in,
                              void* d_out, int out_size, void* d_ws, size_t ws_size,
                              hipStream_t stream) {
  const int*   x      = (const int*)d_in[0];    // [1024][512] int32
  const float* kern   = (const float*)d_in[1];  // [128][1024]
  const float* rec    = (const float*)d_in[2];  // [256][1024]
  const float* bias   = (const float*)d_in[3];  // [1024]
  const float* dw     = (const float*)d_in[4];  // [256][128]
  const float* db     = (const float*)d_in[5];  // [128]
  float* outp = (float*)d_out;                  // [1024][128]

  unsigned char* ws = (unsigned char*)d_ws;
  unsigned short* recT = (unsigned short*)(ws);            // 512 KB
  unsigned short* kb2  = (unsigned short*)(ws + 524288);   // 256 KB
  unsigned short* dwT  = (unsigned short*)(ws + 786432);   //  64 KB

  prep_kernel<<<1664, 256, 0, stream>>>(rec, kern, bias, dw, recT, kb2, dwT);
  lstm_kernel<<<64, 512, 0, stream>>>(recT, kb2, dwT, x, db, outp);
}